// Round 4
// baseline (289.054 us; speedup 1.0000x reference)
//
#include <hip/hip_runtime.h>

// Problem constants (from reference)
#define VOCAB 50257
#define SEQ   2048
#define EMB   512
#define BATCH 8

// Native clang vector type — accepted by __builtin_nontemporal_store
// (HIP_vector_type float4 is not).
typedef float floatx4 __attribute__((ext_vector_type(4)));

// Single fused kernel: direct strided gather from W_emb (EMB, VOCAB) + W_pos add.
// One thread per output float4. Within a wave, all 64 lanes share one (b,s)
// token (t is wave-uniform), lanes cover 64 consecutive e4 slots.
// The 4 loads per lane are strided by VOCAB (scattered lines) — W_emb fits in
// the 256 MiB L3, so each line is fetched from HBM once and reused ~5x from L3.
// Output store is coalesced 1 KiB/wave, nontemporal to keep streaming writes
// from evicting W_emb lines.
__global__ __launch_bounds__(256)
void fused_gather_k(const int* __restrict__ tokens,
                    const float* __restrict__ W_emb,     // (EMB, VOCAB)
                    const floatx4* __restrict__ Wpos,    // (SEQ, EMB/4)
                    floatx4* __restrict__ out) {         // (B*S, EMB/4)
    const int idx = blockIdx.x * blockDim.x + threadIdx.x;
    const int e4  = idx & (EMB / 4 - 1);    // 0..127
    const int ts  = idx >> 7;               // b*SEQ + s
    const int s   = ts & (SEQ - 1);
    const int t   = tokens[ts];             // wave-uniform

    const size_t base = (size_t)(4 * e4) * VOCAB + (size_t)t;
    floatx4 r;
    r.x = W_emb[base];
    r.y = W_emb[base + (size_t)VOCAB];
    r.z = W_emb[base + (size_t)(2 * VOCAB)];
    r.w = W_emb[base + (size_t)(3 * VOCAB)];

    const floatx4 p = Wpos[(size_t)s * (EMB / 4) + e4];
    const floatx4 o = r + p;
    __builtin_nontemporal_store(o, &out[idx]);
}

extern "C" void kernel_launch(void* const* d_in, const int* in_sizes, int n_in,
                              void* d_out, int out_size, void* d_ws, size_t ws_size,
                              hipStream_t stream) {
    const int*   tokens = (const int*)d_in[0];
    const float* W_emb  = (const float*)d_in[1];   // (EMB, VOCAB)
    const float* W_pos  = (const float*)d_in[2];   // (SEQ, EMB)
    float*       out    = (float*)d_out;           // (BATCH, SEQ, EMB)

    const int n_out4  = BATCH * SEQ * (EMB / 4);   // 2,097,152
    const int gblocks = n_out4 / 256;              // 8192

    fused_gather_k<<<gblocks, 256, 0, stream>>>(tokens, W_emb,
                                                (const floatx4*)W_pos,
                                                (floatx4*)out);
}

// Round 5
// 185.025 us; speedup vs baseline: 1.5622x; 1.5622x over previous
//
#include <hip/hip_runtime.h>

// Problem constants (from reference)
#define VOCAB 50257
#define SEQ   2048
#define EMB   512
#define BATCH 8
#define NTOK  (BATCH * SEQ)   // 16384

typedef float floatx4 __attribute__((ext_vector_type(4)));

// ---------------------------------------------------------------------------
// Workspace layout:
//   [0 .. VOCAB) ints          : map  (vocab -> slot, -1 if unused)
//   [VOCAB_PAD] int            : counter
//   [256 KiB ...]              : WT_c  float[<=NTOK][EMB]  (~33.5 MB max)
// ---------------------------------------------------------------------------
#define MAP_INTS      VOCAB
#define COUNTER_IDX   50432            // padded past VOCAB
#define WTC_OFFSET    (256 * 1024)     // bytes

__global__ __launch_bounds__(256)
void init_map_k(int* __restrict__ map, int* __restrict__ counter) {
    const int i = blockIdx.x * 256 + threadIdx.x;
    if (i < VOCAB) map[i] = -1;
    if (i == 0) *counter = 0;
}

__global__ __launch_bounds__(256)
void build_map_k(const int* __restrict__ tokens, int* __restrict__ map,
                 int* __restrict__ counter) {
    const int i = blockIdx.x * 256 + threadIdx.x;
    if (i >= NTOK) return;
    const int t = tokens[i];
    const int old = atomicCAS(&map[t], -1, -2);
    if (old == -1) {
        const int slot = atomicAdd(counter, 1);
        atomicExch(&map[t], slot);   // final value; visible to later kernels
    }
}

// Transpose only the USED columns of W_emb (EMB, VOCAB) into WT_c (slot, EMB).
// Reads are fully coalesced (256 B/wave-inst rows); writes only ~28% of
// columns (ballot-compacted used list). All LDS phases <=2-way bank aliasing.
__global__ __launch_bounds__(256)
void transpose_compact_k(const float* __restrict__ in,   // (EMB, VOCAB)
                         const int* __restrict__ map,
                         float* __restrict__ WTc) {      // (nslots, EMB)
    __shared__ float tile[64][65];
    __shared__ int used_v[64];
    __shared__ int used_s[64];
    __shared__ int nused_s;
    const int v0 = blockIdx.x * 64;
    const int e0 = blockIdx.y * 64;
    const int tx = threadIdx.x;   // 0..63 (lane)
    const int ty = threadIdx.y;   // 0..3  (wave)
    const int v  = v0 + tx;
    const bool vok = (v < VOCAB);

    // Stage 64x64 tile; each wave-inst reads 256 B contiguous of one e-row.
#pragma unroll
    for (int j = 0; j < 16; ++j) {
        const int e_l = 4 * j + ty;
        if (vok) tile[e_l][tx] = in[(size_t)(e0 + e_l) * VOCAB + v];
    }
    // Wave 0 compacts the used-column list via ballot.
    if (ty == 0) {
        const int s = vok ? map[v] : -1;
        const unsigned long long mask = __ballot(s >= 0);
        const int pos = __popcll(mask & ((1ull << tx) - 1ull));
        if (s >= 0) { used_v[pos] = tx; used_s[pos] = s; }
        if (tx == 0) nused_s = (int)__popcll(mask);
    }
    __syncthreads();
    const int nused = nused_s;
    // Each used column becomes one contiguous 256 B row-segment write.
    for (int u = ty; u < nused; u += 4) {
        const int v_l = used_v[u];
        const int s   = used_s[u];
        WTc[(size_t)s * EMB + e0 + tx] = tile[tx][v_l];  // (tx+v_l)%32: 2-way, free
    }
}

// Final gather from the compact table + fused positional add.
__global__ __launch_bounds__(256)
void gather_k(const int* __restrict__ tokens,
              const int* __restrict__ map,
              const floatx4* __restrict__ WTc,   // (nslots, EMB/4)
              const floatx4* __restrict__ Wpos,  // (SEQ, EMB/4)
              floatx4* __restrict__ out) {       // (B*S, EMB/4)
    const int idx = blockIdx.x * blockDim.x + threadIdx.x;
    const int e4  = idx & (EMB / 4 - 1);
    const int ts  = idx >> 7;               // wave-uniform
    const int s   = ts & (SEQ - 1);
    const int slot = map[tokens[ts]];
    const floatx4 emb = WTc[(size_t)slot * (EMB / 4) + e4];
    const floatx4 p   = Wpos[(size_t)s * (EMB / 4) + e4];
    __builtin_nontemporal_store(emb + p, &out[idx]);
}

// Fallback: direct strided gather (correct anywhere, slow).
__global__ __launch_bounds__(256)
void gather_direct_k(const int* __restrict__ tokens,
                     const float* __restrict__ W_emb,
                     const floatx4* __restrict__ Wpos,
                     floatx4* __restrict__ out) {
    const int idx = blockIdx.x * blockDim.x + threadIdx.x;
    const int e4  = idx & (EMB / 4 - 1);
    const int ts  = idx >> 7;
    const int s   = ts & (SEQ - 1);
    const int t   = tokens[ts];
    const size_t base = (size_t)(4 * e4) * VOCAB + (size_t)t;
    floatx4 r;
    r.x = W_emb[base];
    r.y = W_emb[base + (size_t)VOCAB];
    r.z = W_emb[base + (size_t)(2 * VOCAB)];
    r.w = W_emb[base + (size_t)(3 * VOCAB)];
    __builtin_nontemporal_store(r + Wpos[(size_t)s * (EMB / 4) + e4], &out[idx]);
}

extern "C" void kernel_launch(void* const* d_in, const int* in_sizes, int n_in,
                              void* d_out, int out_size, void* d_ws, size_t ws_size,
                              hipStream_t stream) {
    const int*   tokens = (const int*)d_in[0];
    const float* W_emb  = (const float*)d_in[1];   // (EMB, VOCAB)
    const float* W_pos  = (const float*)d_in[2];   // (SEQ, EMB)
    float*       out    = (float*)d_out;           // (BATCH, SEQ, EMB)

    const int n_out4  = BATCH * SEQ * (EMB / 4);   // 2,097,152
    const int gblocks = n_out4 / 256;              // 8192

    const size_t need = WTC_OFFSET + (size_t)NTOK * EMB * sizeof(float); // ~33.8 MB
    if (ws_size >= need) {
        int*   map     = (int*)d_ws;
        int*   counter = map + COUNTER_IDX;
        float* WTc     = (float*)((char*)d_ws + WTC_OFFSET);

        init_map_k<<<(VOCAB + 255) / 256, 256, 0, stream>>>(map, counter);
        build_map_k<<<NTOK / 256, 256, 0, stream>>>(tokens, map, counter);
        transpose_compact_k<<<dim3((VOCAB + 63) / 64, EMB / 64), dim3(64, 4), 0, stream>>>(
            W_emb, map, WTc);
        gather_k<<<gblocks, 256, 0, stream>>>(tokens, map, (const floatx4*)WTc,
                                              (const floatx4*)W_pos, (floatx4*)out);
    } else {
        gather_direct_k<<<gblocks, 256, 0, stream>>>(tokens, W_emb,
                                                     (const floatx4*)W_pos,
                                                     (floatx4*)out);
    }
}